// Round 9
// baseline (136.693 us; speedup 1.0000x reference)
//
#include <hip/hip_runtime.h>
#include <cfloat>
#include <cmath>

#define N_TOK (32*4096)                 // 131072 tokens
#define DIM   64
#define N_E   1024

typedef __attribute__((ext_vector_type(8))) __bf16 bf16x8;
typedef __attribute__((ext_vector_type(4))) float  f32x4;
typedef unsigned int u32;

// ws layout (bytes)
#define WS_CN2    0u                    // 1024 f32 (-0.5*||e||^2)           (4 KB)
#define WS_CBF    4096u                 // fragment-ordered bf16 hi+lo       (256 KB)
#define WS_GIDX   266240u               // 131072 int winner ids             (512 KB)
#define WS_COUNTS 790528u               // 1024 u32                          (4 KB)
#define WS_SSEA   794624u               // 64 f32 partial SSE cells
#define WS_DONE   794880u               // 1 u32

// async global->LDS, 16 B per lane; LDS dest must be wave-uniform base + lane*16
__device__ __forceinline__ void async_cp16(const void* g, void* l) {
    __builtin_amdgcn_global_load_lds((const __attribute__((address_space(1))) u32*)g,
                                     (__attribute__((address_space(3))) u32*)l, 16, 0, 0);
}

// Codebook -> MFMA B-fragment order (bf16 hi/lo):
//   cbF[cblk*16384 + plane*8192 + ch*1024 + kf*512 + (q*16+n)*8 + j]
__global__ __launch_bounds__(256) void prep_kernel(const float* __restrict__ cb,
        float* __restrict__ cn2, __bf16* __restrict__ cbF,
        unsigned* __restrict__ counts, float* __restrict__ ssea, unsigned* __restrict__ done) {
    const int t = threadIdx.x;
    const int k = blockIdx.x * 32 + (t >> 3);        // code 0..1023
    const int oct = t & 7;
    if (t < 32) counts[blockIdx.x * 32 + t] = 0u;
    if (blockIdx.x == 0 && t < 64) ssea[t] = 0.f;
    if (blockIdx.x == 0 && t == 0) *done = 0u;

    const float4 a = *(const float4*)(cb + (size_t)k * DIM + oct * 8);
    const float4 b = *(const float4*)(cb + (size_t)k * DIM + oct * 8 + 4);
    float v[8] = {a.x,a.y,a.z,a.w,b.x,b.y,b.z,b.w};
    bf16x8 hv, lv;
    float nrm = 0.f;
#pragma unroll
    for (int j = 0; j < 8; ++j) {
        float f = v[j];
        nrm = fmaf(f, f, nrm);
        __bf16 h = (__bf16)f;
        __bf16 l = (__bf16)(f - (float)h);
        hv[j] = h; lv[j] = l;
    }
    const int cblk = k >> 7, local = k & 127;
    const int ch = local >> 4, n = local & 15;
    const int kf = oct >> 2, q = oct & 3;
    __bf16* base = cbF + (size_t)cblk * 16384 + ch * 1024 + kf * 512 + q * 128 + n * 8;
    *(bf16x8*)(base) = hv;
    *(bf16x8*)(base + 8192) = lv;
    nrm += __shfl_xor(nrm, 1, 64);
    nrm += __shfl_xor(nrm, 2, 64);
    nrm += __shfl_xor(nrm, 4, 64);
    if (oct == 0) cn2[k] = -0.5f * nrm;
}

// R8 shape + software-pipelined staging: double-buffered LDS, prefetch of
// cblk+1 issued BEFORE compute on cblk -> the vmcnt(0) drain at the single
// per-cblk barrier finds loads already landed. Barriers: 16 -> 9 per block.
__global__ __launch_bounds__(256, 2) void fused_kernel(const float* __restrict__ z,
        const __bf16* __restrict__ cbF, const float* __restrict__ cn2,
        const float* __restrict__ cb, float* __restrict__ out,
        int* __restrict__ gidx, float* __restrict__ ssea) {
    __shared__ __bf16 lbuf[2][16384];                // 2 x 32 KB double buffer
    __shared__ float  lcnAll[1024];                  // all code norms, loaded once
    __shared__ int    lidx[256];
    const int t    = threadIdx.x;
    const int lane = t & 63;
    const int w    = t >> 6;
    const int n    = lane & 15;                      // MFMA col / code-in-chunk
    const int q    = lane >> 4;                      // k-octet selector
    const int wtok = blockIdx.x * 256 + w * 64;

    // Issue cblk-0 staging FIRST: DMA overlaps the A-frag load+convert below.
#pragma unroll
    for (int i = 0; i < 8; ++i) {
        int off = (i*256 + t) * 16;                  // bytes; lane-linear per wave
        async_cp16((const char*)cbF + off, (char*)lbuf[0] + off);
    }

    // A fragments (64 tokens/wave as 4 tiles x 2 K-halves), bf16 hi/lo in regs;
    // pn[tile] = exact fp32 ||z||^2 (after q-reduce).
    bf16x8 ah[4][2], al[4][2];
    float pn[4];
    const float4* z4 = (const float4*)z;
#pragma unroll
    for (int tile = 0; tile < 4; ++tile) {
        int tok = wtok + tile*16 + n;
        float nrm = 0.f;
#pragma unroll
        for (int kf = 0; kf < 2; ++kf) {
            float4 p0 = z4[(size_t)tok*16 + kf*8 + q*2];
            float4 p1 = z4[(size_t)tok*16 + kf*8 + q*2 + 1];
            float v[8] = {p0.x,p0.y,p0.z,p0.w,p1.x,p1.y,p1.z,p1.w};
            bf16x8 hv, lv;
#pragma unroll
            for (int j = 0; j < 8; ++j) {
                float f = v[j];
                nrm = fmaf(f, f, nrm);
                __bf16 h = (__bf16)f;
                __bf16 l = (__bf16)(f - (float)h);
                hv[j] = h; lv[j] = l;
            }
            ah[tile][kf] = hv; al[tile][kf] = lv;
        }
        nrm += __shfl_xor(nrm, 16, 64);
        nrm += __shfl_xor(nrm, 32, 64);
        pn[tile] = nrm;
    }

    // All 1024 code norms -> LDS once (replaces per-cblk lcn staging).
#pragma unroll
    for (int i = 0; i < 4; ++i) lcnAll[t + 256*i] = cn2[t + 256*i];

    float best[16];
#pragma unroll
    for (int s = 0; s < 16; ++s) best[s] = -3.4e38f;

    __syncthreads();                                 // buf0 + lcnAll ready

    for (int cblk = 0; cblk < 8; ++cblk) {
        const int cur = cblk & 1;
        // Prefetch next cblk NOW — has the whole compute phase to land.
        if (cblk < 7) {
            const char* gsrc = (const char*)(cbF + (size_t)(cblk + 1) * 16384);
            char* ldst = (char*)lbuf[cur ^ 1];
#pragma unroll
            for (int i = 0; i < 8; ++i) {
                int off = (i*256 + t) * 16;
                async_cp16(gsrc + off, ldst + off);
            }
        }
        const __bf16* lb = lbuf[cur];
        const float* lcnb = lcnAll + cblk*128;
#pragma unroll 2
        for (int ch = 0; ch < 8; ++ch) {
            const int fb = ch*1024 + lane*8;         // conflict-free: lane*16 B
            bf16x8 bh0 = *(const bf16x8*)(lb + fb);
            bf16x8 bh1 = *(const bf16x8*)(lb + fb + 512);
            bf16x8 bl0 = *(const bf16x8*)(lb + fb + 8192);
            bf16x8 bl1 = *(const bf16x8*)(lb + fb + 8704);
            const float cnv = lcnb[ch*16 + n];
            const u32 codebits = (u32)(cblk*128 + ch*16 + n);
#pragma unroll
            for (int tile = 0; tile < 4; ++tile) {
                f32x4 acc = {cnv, cnv, cnv, cnv};
                acc = __builtin_amdgcn_mfma_f32_16x16x32_bf16(ah[tile][0], bh0, acc, 0, 0, 0);
                acc = __builtin_amdgcn_mfma_f32_16x16x32_bf16(ah[tile][1], bh1, acc, 0, 0, 0);
                acc = __builtin_amdgcn_mfma_f32_16x16x32_bf16(al[tile][0], bh0, acc, 0, 0, 0);
                acc = __builtin_amdgcn_mfma_f32_16x16x32_bf16(al[tile][1], bh1, acc, 0, 0, 0);
                acc = __builtin_amdgcn_mfma_f32_16x16x32_bf16(ah[tile][0], bl0, acc, 0, 0, 0);
                acc = __builtin_amdgcn_mfma_f32_16x16x32_bf16(ah[tile][1], bl1, acc, 0, 0, 0);
#pragma unroll
                for (int r = 0; r < 4; ++r) {
                    float packed = __uint_as_float((__float_as_uint(acc[r]) & 0xFFFFFC00u) | codebits);
                    best[tile*4 + r] = fmaxf(best[tile*4 + r], packed);
                }
            }
        }
        __syncthreads();                             // publish next buf; drain is ~free
    }

    // Winner reduce; ids -> LDS then plain coalesced store (no counts atomics).
    float sse_acc = 0.f;
#pragma unroll
    for (int s = 0; s < 16; ++s) {
        float bs = best[s];
#pragma unroll
        for (int m = 8; m >= 1; m >>= 1)
            bs = fmaxf(bs, __shfl_xor(bs, m, 64));
        u32 bits = __float_as_uint(bs);
        int id = (int)(bits & 0x3FFu);
        float sc = __uint_as_float(bits & 0xFFFFFC00u);
        float nrm = __shfl(pn[s >> 2], (q << 2) | (s & 3), 64);
        if (n == 0) {
            lidx[w*64 + (s >> 2)*16 + q*4 + (s & 3)] = id;
            sse_acc += fmaf(-2.f, sc, nrm);          // d = ||z||^2 - 2*score
        }
    }
    sse_acc += __shfl_xor(sse_acc, 16, 64);
    sse_acc += __shfl_xor(sse_acc, 32, 64);
    if (lane == 0) atomicAdd(&ssea[(blockIdx.x*4 + w) & 63], sse_acc);

    int myid = lidx[w*64 + lane];                    // wave-local LDS, no barrier needed
    gidx[wtok + lane] = myid;                        // coalesced id publish

    // z_q write: wave's 64 tokens, readlane id -> independent coalesced row copies.
    const size_t obase = 1 + (size_t)wtok * DIM;
#pragma unroll
    for (int i = 0; i < 64; ++i) {
        int id = __shfl(myid, i, 64);                // compile-time lane -> v_readlane
        float qv = cb[(size_t)id * DIM + lane];
        out[obase + (size_t)i * DIM + lane] = qv;
    }
}

// Histogram from gidx via per-block LDS counts, then 32 spread global adds;
// last block computes entropy + loss.
__global__ __launch_bounds__(256) void hist_kernel(const int* __restrict__ gidx,
        unsigned* __restrict__ counts, const float* __restrict__ ssea,
        unsigned* __restrict__ done, float* __restrict__ out) {
    __shared__ unsigned hist[1024];
    __shared__ float fred[4];
    __shared__ u32 lastflag;
    const int t = threadIdx.x;
#pragma unroll
    for (int i = 0; i < 4; ++i) hist[t + 256*i] = 0u;
    __syncthreads();
    const int base = blockIdx.x * 4096;
#pragma unroll
    for (int i = 0; i < 16; ++i) {
        int id = gidx[base + i*256 + t];
        atomicAdd(&hist[id], 1u);
    }
    __syncthreads();
#pragma unroll
    for (int i = 0; i < 4; ++i) {
        unsigned v = hist[t + 256*i];
        if (v) atomicAdd(&counts[t + 256*i], v);
    }
    __threadfence();
    __syncthreads();
    if (t == 0) lastflag = (atomicAdd(done, 1u) == 31u) ? 1u : 0u;
    __syncthreads();
    if (lastflag) {
        float acc = 0.f;
#pragma unroll
        for (int i = 0; i < 4; ++i) {
            u32 cv = atomicAdd(&counts[t + 256*i], 0u);      // coherent read
            float p = (float)cv * (1.0f / 131072.0f);
            acc += p * logf(p + 1e-10f);
        }
#pragma unroll
        for (int off = 32; off; off >>= 1) acc += __shfl_down(acc, off, 64);
        if ((t & 63) == 0) fred[t >> 6] = acc;
        float sv = (t < 64) ? ssea[t] : 0.f;                 // prior-dispatch data
#pragma unroll
        for (int off = 32; off; off >>= 1) sv += __shfl_down(sv, off, 64);
        __syncthreads();
        if (t == 0) {
            float H = -((fred[0] + fred[1]) + (fred[2] + fred[3]));
            out[0] = 1.25f * sv * (1.0f / 8388608.0f);       // (1+BETA)*MSE
            out[8388609] = expf(H);
        }
    }
}

extern "C" void kernel_launch(void* const* d_in, const int* in_sizes, int n_in,
                              void* d_out, int out_size, void* d_ws, size_t ws_size,
                              hipStream_t stream) {
    const float* z  = (const float*)d_in[0];
    const float* cb = (const float*)d_in[1];
    float* out = (float*)d_out;
    char* ws = (char*)d_ws;
    float*    cn2    = (float*)(ws + WS_CN2);
    __bf16*   cbF    = (__bf16*)(ws + WS_CBF);
    int*      gidx   = (int*)(ws + WS_GIDX);
    unsigned* counts = (unsigned*)(ws + WS_COUNTS);
    float*    ssea   = (float*)(ws + WS_SSEA);
    unsigned* done   = (unsigned*)(ws + WS_DONE);

    prep_kernel<<<32, 256, 0, stream>>>(cb, cn2, cbF, counts, ssea, done);
    fused_kernel<<<N_TOK/256, 256, 0, stream>>>(z, cbF, cn2, cb, out, gidx, ssea);
    hist_kernel<<<32, 256, 0, stream>>>(gidx, counts, ssea, done, out);
}